// Round 2
// baseline (249.625 us; speedup 1.0000x reference)
//
#include <hip/hip_runtime.h>
#include <math.h>

#define BATCH 64
#define NCH 7
#define NPATCH 512
#define DMODEL 128
#define BC (BATCH * NCH)                 // 448
#define CHUNKS 4
#define ROWS_PER_CHUNK (NPATCH / CHUNKS) // 128
#define D4 (DMODEL / 4)                  // 32 float4 per row

// ---------------------------------------------------------------------------
// Kernel 1: partial mean-pool over patches.
// grid = BC*CHUNKS = 1792 blocks (exactly 7 per CU), block = 256 threads.
// Each block sums 128 rows x 128 floats (64 KB contiguous), float4-coalesced,
// and writes a 128-float partial sum to ws.
// ---------------------------------------------------------------------------
__global__ __launch_bounds__(256) void k_pool(const float* __restrict__ x,
                                              float* __restrict__ partial) {
    const int blk   = blockIdx.x;
    const int bc    = blk >> 2;
    const int chunk = blk & 3;
    const float4* xp = reinterpret_cast<const float4*>(
        x + (size_t)bc * (NPATCH * DMODEL) + (size_t)chunk * (ROWS_PER_CHUNK * DMODEL));

    const int t   = threadIdx.x;
    const int col = t & 31;   // float4 column 0..31
    const int row = t >> 5;   // 0..7

    float4 acc = make_float4(0.f, 0.f, 0.f, 0.f);
    for (int n = row; n < ROWS_PER_CHUNK; n += 8) {
        float4 v = xp[n * D4 + col];
        acc.x += v.x; acc.y += v.y; acc.z += v.z; acc.w += v.w;
    }

    __shared__ float4 red[256];
    red[t] = acc;
    __syncthreads();
    if (t < 128) {
        float4 o = red[t + 128];
        red[t].x += o.x; red[t].y += o.y; red[t].z += o.z; red[t].w += o.w;
    }
    __syncthreads();
    if (t < 64) {
        float4 o = red[t + 64];
        red[t].x += o.x; red[t].y += o.y; red[t].z += o.z; red[t].w += o.w;
    }
    __syncthreads();
    if (t < 32) {
        float4 a = red[t];
        float4 o = red[t + 32];
        a.x += o.x; a.y += o.y; a.z += o.z; a.w += o.w;
        reinterpret_cast<float4*>(partial)[(size_t)blk * D4 + t] = a;
    }
}

// ---------------------------------------------------------------------------
// Kernel 2: the whole 2-layer GNN on pooled features. One block per batch.
// All state lives in LDS; total compute ~30 MFLOP across the grid.
// ---------------------------------------------------------------------------
__global__ __launch_bounds__(256) void k_gnn(const float* __restrict__ partial,
                                             const float* __restrict__ adjn,
                                             const float* __restrict__ adjl,
                                             const float* __restrict__ W,
                                             const float* __restrict__ bias,
                                             const float* __restrict__ gamma,
                                             const float* __restrict__ beta,
                                             float* __restrict__ hfinal) {
    const int b = blockIdx.x;
    const int t = threadIdx.x;

    __shared__ float s_adj[NCH * NCH];
    __shared__ float s_h[NCH][DMODEL];
    __shared__ float s_hn[NCH][DMODEL];
    __shared__ float s_pre[NCH][DMODEL];
    __shared__ float s_mu[NCH];
    __shared__ float s_rstd[NCH];

    if (t < NCH * NCH) {
        float a = adjl[t];
        s_adj[t] = adjn[t] + 1.0f / (1.0f + expf(-a));  // exact sigmoid
    }

    // Load pooled h: sum the 4 chunk-partials, divide by NPATCH.
    for (int idx = t; idx < NCH * DMODEL; idx += 256) {
        const int c = idx >> 7;
        const int d = idx & 127;
        const float* p = partial + ((size_t)(b * NCH + c) * CHUNKS) * DMODEL + d;
        float s = p[0] + p[DMODEL] + p[2 * DMODEL] + p[3 * DMODEL];
        s_h[c][d] = s * (1.0f / NPATCH);
    }
    __syncthreads();

    for (int l = 0; l < 2; ++l) {
        // Graph propagation: hn[c][d] = sum_j adj[c][j] * h[j][d]
        for (int idx = t; idx < NCH * DMODEL; idx += 256) {
            const int c = idx >> 7;
            const int d = idx & 127;
            float s = 0.f;
#pragma unroll
            for (int j = 0; j < NCH; ++j) s += s_adj[c * NCH + j] * s_h[j][d];
            s_hn[c][d] = s;
        }
        __syncthreads();

        // Linear (y = hn W^T + b) + exact GELU + residual
        const float* Wl = W + (size_t)l * DMODEL * DMODEL;
        const float* bl = bias + l * DMODEL;
        for (int idx = t; idx < NCH * DMODEL; idx += 256) {
            const int c = idx >> 7;
            const int o = idx & 127;
            const float4* wrow = reinterpret_cast<const float4*>(Wl + (size_t)o * DMODEL);
            const float4* hr   = reinterpret_cast<const float4*>(&s_hn[c][0]);
            float dot = 0.f;
#pragma unroll
            for (int k = 0; k < D4; ++k) {
                float4 w4 = wrow[k];
                float4 h4 = hr[k];
                dot += w4.x * h4.x + w4.y * h4.y + w4.z * h4.z + w4.w * h4.w;
            }
            float v = dot + bl[o];
            float g = 0.5f * v * (1.0f + erff(v * 0.70710678118654752f));
            s_pre[c][o] = s_h[c][o] + g;
        }
        __syncthreads();

        // LayerNorm stats: 32 lanes per channel row (7 rows -> 224 threads)
        if (t < NCH * 32) {
            const int c    = t >> 5;
            const int lane = t & 31;
            float sum = 0.f, sq = 0.f;
#pragma unroll
            for (int k = 0; k < 4; ++k) {
                float v = s_pre[c][lane * 4 + k];
                sum += v;
                sq  += v * v;
            }
            for (int off = 16; off > 0; off >>= 1) {
                sum += __shfl_down(sum, off, 32);
                sq  += __shfl_down(sq, off, 32);
            }
            if (lane == 0) {
                float mu  = sum * (1.0f / DMODEL);
                float var = sq * (1.0f / DMODEL) - mu * mu;
                s_mu[c]   = mu;
                s_rstd[c] = rsqrtf(var + 1e-5f);
            }
        }
        __syncthreads();

        // Normalize + affine -> next h
        const float* gl = gamma + l * DMODEL;
        const float* be = beta + l * DMODEL;
        for (int idx = t; idx < NCH * DMODEL; idx += 256) {
            const int c = idx >> 7;
            const int d = idx & 127;
            s_h[c][d] = (s_pre[c][d] - s_mu[c]) * s_rstd[c] * gl[d] + be[d];
        }
        __syncthreads();
    }

    for (int idx = t; idx < NCH * DMODEL; idx += 256)
        hfinal[(size_t)b * NCH * DMODEL + idx] = s_h[idx >> 7][idx & 127];
}

// ---------------------------------------------------------------------------
// Kernel 3: out = x + broadcast(hfinal).
// grid = BC*CHUNKS = 1792 blocks; each block owns one (bc, 128-row chunk),
// loads its 128-float h row into LDS ONCE, then streams x -> out.
// Pure streaming: 1 x-read + 1 out-write per element, no repeated h loads.
// ---------------------------------------------------------------------------
__global__ __launch_bounds__(256) void k_add(const float* __restrict__ x,
                                             const float* __restrict__ hfinal,
                                             float* __restrict__ out) {
    const int blk   = blockIdx.x;
    const int bc    = blk >> 2;
    const int chunk = blk & 3;
    const size_t base = (size_t)bc * (NPATCH * DMODEL) + (size_t)chunk * (ROWS_PER_CHUNK * DMODEL);
    const float4* x4 = reinterpret_cast<const float4*>(x + base);
    float4*       o4 = reinterpret_cast<float4*>(out + base);

    const int t   = threadIdx.x;
    const int col = t & 31;   // float4 column 0..31
    const int row = t >> 5;   // 0..7

    __shared__ float4 s_h4[D4];
    if (t < D4) s_h4[t] = reinterpret_cast<const float4*>(hfinal + (size_t)bc * DMODEL)[t];
    __syncthreads();

    const float4 hv = s_h4[col];
#pragma unroll 4
    for (int n = row; n < ROWS_PER_CHUNK; n += 8) {
        float4 v = x4[n * D4 + col];
        v.x += hv.x; v.y += hv.y; v.z += hv.z; v.w += hv.w;
        o4[n * D4 + col] = v;
    }
}

extern "C" void kernel_launch(void* const* d_in, const int* in_sizes, int n_in,
                              void* d_out, int out_size, void* d_ws, size_t ws_size,
                              hipStream_t stream) {
    const float* x     = (const float*)d_in[0];
    const float* adjn  = (const float*)d_in[1];
    const float* adjl  = (const float*)d_in[2];
    const float* W     = (const float*)d_in[3];
    const float* bias  = (const float*)d_in[4];
    const float* gamma = (const float*)d_in[5];
    const float* beta  = (const float*)d_in[6];
    float* out = (float*)d_out;

    // ws layout (floats): [BC*CHUNKS*DMODEL] partials, then [BC*DMODEL] hfinal
    float* partial = (float*)d_ws;
    float* hfinal  = partial + (size_t)BC * CHUNKS * DMODEL;

    k_pool<<<BC * CHUNKS, 256, 0, stream>>>(x, partial);
    k_gnn<<<BATCH, 256, 0, stream>>>(partial, adjn, adjl, W, bias, gamma, beta, hfinal);
    k_add<<<BC * CHUNKS, 256, 0, stream>>>(x, hfinal, out);
}